// Round 2
// baseline (2847.076 us; speedup 1.0000x reference)
//
#include <hip/hip_runtime.h>
#include <hip/hip_bf16.h>
#include <cmath>

#define TBL (1 << 19)   // T = 2^19 hash table entries per level (power of two)

__device__ __forceinline__ float relu_f(float x) { return fmaxf(x, 0.0f); }

__global__ __launch_bounds__(256, 2)
void nerf_fused(const float* __restrict__ xyz,
                const float* __restrict__ dirv,
                const float* __restrict__ table,
                const float* __restrict__ ws1,   // (32,64)
                const float* __restrict__ ws2,   // (64,17)
                const float* __restrict__ wr1,   // (32,64)
                const float* __restrict__ wr2,   // (64,64)
                const float* __restrict__ wr3,   // (64,3)
                float* __restrict__ out,
                int n)
{
    // res_l = floor(16 * 1.3819^l); dense iff (res+1)^3 <= 2^19  (l = 0..4)
    constexpr unsigned RES[16] = {16, 22, 30, 42, 58, 80, 111, 153,
                                  212, 294, 406, 561, 775, 1072, 1481, 2047};

    int i = blockIdx.x * 256 + threadIdx.x;
    if (i >= n) return;

    const float px_ = xyz[3 * i + 0];
    const float py_ = xyz[3 * i + 1];
    const float pz_ = xyz[3 * i + 2];

    // ---------------- hash-grid encode: 32 features ----------------
    float enc[32];
#pragma unroll
    for (int l = 0; l < 16; ++l) {
        const unsigned res = RES[l];
        const float fr = (float)res;
        const float posx = px_ * fr, posy = py_ * fr, posz = pz_ * fr;
        const float fx = floorf(posx), fy = floorf(posy), fz = floorf(posz);
        const float wx = posx - fx, wy = posy - fy, wz = posz - fz;
        const unsigned x0 = (unsigned)fx, y0 = (unsigned)fy, z0 = (unsigned)fz;
        const float* tb = table + (size_t)l * (TBL * 2);
        float a0 = 0.0f, a1 = 0.0f;
#pragma unroll
        for (int c = 0; c < 8; ++c) {
            const unsigned cx = x0 + (c & 1);
            const unsigned cy = y0 + ((c >> 1) & 1);
            const unsigned cz = z0 + ((c >> 2) & 1);
            unsigned idx;
            if (l < 5) {
                const unsigned s = res + 1u;
                idx = cx + cy * s + cz * (s * s);
            } else {
                idx = (cx * 1u) ^ (cy * 2654435761u) ^ (cz * 805459861u);
                idx &= (unsigned)(TBL - 1);
            }
            const float w = ((c & 1) ? wx : 1.0f - wx) *
                            ((c & 2) ? wy : 1.0f - wy) *
                            ((c & 4) ? wz : 1.0f - wz);
            const float2 f = *reinterpret_cast<const float2*>(tb + 2u * idx);
            a0 = fmaf(f.x, w, a0);
            a1 = fmaf(f.y, w, a1);
        }
        enc[2 * l + 0] = a0;
        enc[2 * l + 1] = a1;
    }

    // ---------------- sigma MLP: enc(32) -> 64 -> 17 ----------------
    float h[64];
#pragma unroll
    for (int j = 0; j < 64; ++j) h[j] = 0.0f;
#pragma unroll
    for (int k = 0; k < 32; ++k) {
        const float e = enc[k];
#pragma unroll
        for (int j = 0; j < 64; ++j) h[j] = fmaf(e, ws1[k * 64 + j], h[j]);
    }
#pragma unroll
    for (int j = 0; j < 64; ++j) h[j] = relu_f(h[j]);

    float geo[17];
#pragma unroll
    for (int j = 0; j < 17; ++j) geo[j] = 0.0f;
#pragma unroll
    for (int k = 0; k < 64; ++k) {
        const float e = h[k];
#pragma unroll
        for (int j = 0; j < 17; ++j) geo[j] = fmaf(e, ws2[k * 17 + j], geo[j]);
    }
    const float sigma = relu_f(geo[0]);

    // ---------------- SH deg-4 of dir*2-1 ----------------
    const float dx = dirv[3 * i + 0] * 2.0f - 1.0f;
    const float dy = dirv[3 * i + 1] * 2.0f - 1.0f;
    const float dz = dirv[3 * i + 2] * 2.0f - 1.0f;
    const float x2 = dx * dx, y2 = dy * dy, z2 = dz * dz;
    const float xy = dx * dy, yz = dy * dz, xz = dx * dz;

    float rin[32];
    rin[0]  = 0.28209479177387814f;
    rin[1]  = -0.48860251190291987f * dy;
    rin[2]  = 0.48860251190291987f * dz;
    rin[3]  = -0.48860251190291987f * dx;
    rin[4]  = 1.0925484305920792f * xy;
    rin[5]  = -1.0925484305920792f * yz;
    rin[6]  = 0.94617469575756f * z2 - 0.31539156525252f;
    rin[7]  = -1.0925484305920792f * xz;
    rin[8]  = 0.5462742152960396f * (x2 - y2);
    rin[9]  = 0.5900435899266435f * dy * (-3.0f * x2 + y2);
    rin[10] = 2.890611442640554f * xy * dz;
    rin[11] = 0.4570457994644657f * dy * (1.0f - 5.0f * z2);
    rin[12] = 0.3731763325901154f * dz * (5.0f * z2 - 3.0f);
    rin[13] = 0.4570457994644657f * dx * (1.0f - 5.0f * z2);
    rin[14] = 1.445305721320277f * dz * (x2 - y2);
    rin[15] = 0.5900435899266435f * dx * (-x2 + 3.0f * y2);
#pragma unroll
    for (int j = 0; j < 16; ++j) rin[16 + j] = geo[1 + j];

    // ---------------- rgb MLP: 32 -> 64 -> 64 -> 3 ----------------
    float g[64];
#pragma unroll
    for (int j = 0; j < 64; ++j) g[j] = 0.0f;
#pragma unroll
    for (int k = 0; k < 32; ++k) {
        const float e = rin[k];
#pragma unroll
        for (int j = 0; j < 64; ++j) g[j] = fmaf(e, wr1[k * 64 + j], g[j]);
    }
#pragma unroll
    for (int j = 0; j < 64; ++j) g[j] = relu_f(g[j]);

    float g2[64];
#pragma unroll
    for (int j = 0; j < 64; ++j) g2[j] = 0.0f;
#pragma unroll
    for (int k = 0; k < 64; ++k) {
        const float e = g[k];
#pragma unroll
        for (int j = 0; j < 64; ++j) g2[j] = fmaf(e, wr2[k * 64 + j], g2[j]);
    }
#pragma unroll
    for (int j = 0; j < 64; ++j) g2[j] = relu_f(g2[j]);

    float r0 = 0.0f, r1 = 0.0f, r2 = 0.0f;
#pragma unroll
    for (int k = 0; k < 64; ++k) {
        const float e = g2[k];
        r0 = fmaf(e, wr3[k * 3 + 0], r0);
        r1 = fmaf(e, wr3[k * 3 + 1], r1);
        r2 = fmaf(e, wr3[k * 3 + 2], r2);
    }

    // ---------------- outputs: sigmoid(rgb) (N,3) then relu(sigma) (N,1), fp32 ----------------
    out[3 * (size_t)i + 0] = 1.0f / (1.0f + expf(-r0));
    out[3 * (size_t)i + 1] = 1.0f / (1.0f + expf(-r1));
    out[3 * (size_t)i + 2] = 1.0f / (1.0f + expf(-r2));
    out[3 * (size_t)n + (size_t)i] = sigma;
}

extern "C" void kernel_launch(void* const* d_in, const int* in_sizes, int n_in,
                              void* d_out, int out_size, void* d_ws, size_t ws_size,
                              hipStream_t stream)
{
    const float* xyz   = (const float*)d_in[0];
    const float* dirv  = (const float*)d_in[1];
    const float* table = (const float*)d_in[2];
    const float* ws1   = (const float*)d_in[3];
    const float* ws2   = (const float*)d_in[4];
    const float* wr1   = (const float*)d_in[5];
    const float* wr2   = (const float*)d_in[6];
    const float* wr3   = (const float*)d_in[7];
    float* out = (float*)d_out;

    const int n = in_sizes[0] / 3;
    dim3 block(256), grid((n + 255) / 256);
    hipLaunchKernelGGL(nerf_fused, grid, block, 0, stream,
                       xyz, dirv, table, ws1, ws2, wr1, wr2, wr3, out, n);
}

// Round 3
// 1450.699 us; speedup vs baseline: 1.9626x; 1.9626x over previous
//
#include <hip/hip_runtime.h>
#include <hip/hip_bf16.h>
#include <cmath>

#define TBL (1 << 19)   // T = 2^19 hash table entries per level (power of two)

__device__ __forceinline__ float relu_f(float x) { return fmaxf(x, 0.0f); }

// Peak live-register budget by construction:
//   encode phase:      enc[32] + ~16 in-flight loads           ~ 56
//   sigma L1:          enc[32] + h[64]                          ~ 100
//   sigma L2:          h[64] + geo[17]                          ~ 85
//   rgb L1:            sh[16] + geo[17] + g[64]                 ~ 100
//   rgb L2 (halved):   g[64] + g2h[32] + r[3]                   ~ 103
// => fits in 128 VGPRs (launch_bounds(256,4)) with no scratch spills.
__global__ __launch_bounds__(256, 4)
void nerf_fused(const float* __restrict__ xyz,
                const float* __restrict__ dirv,
                const float* __restrict__ table,
                const float* __restrict__ ws1,   // (32,64)
                const float* __restrict__ ws2,   // (64,17)
                const float* __restrict__ wr1,   // (32,64)
                const float* __restrict__ wr2,   // (64,64)
                const float* __restrict__ wr3,   // (64,3)
                float* __restrict__ out,
                int n)
{
    // res_l = floor(16 * 1.3819^l); dense iff (res+1)^3 <= 2^19  (l = 0..4)
    constexpr unsigned RES[16] = {16, 22, 30, 42, 58, 80, 111, 153,
                                  212, 294, 406, 561, 775, 1072, 1481, 2047};

    const int i = blockIdx.x * 256 + threadIdx.x;
    if (i >= n) return;

    const float px_ = xyz[3 * (size_t)i + 0];
    const float py_ = xyz[3 * (size_t)i + 1];
    const float pz_ = xyz[3 * (size_t)i + 2];

    // ---------------- hash-grid encode: 32 features ----------------
    float enc[32];
#pragma unroll
    for (int l = 0; l < 16; ++l) {
        const unsigned res = RES[l];
        const float fr = (float)res;
        const float posx = px_ * fr, posy = py_ * fr, posz = pz_ * fr;
        const float fx = floorf(posx), fy = floorf(posy), fz = floorf(posz);
        const float wx = posx - fx, wy = posy - fy, wz = posz - fz;
        const unsigned x0 = (unsigned)fx, y0 = (unsigned)fy, z0 = (unsigned)fz;
        const float* tb = table + (size_t)l * (TBL * 2);
        float a0 = 0.0f, a1 = 0.0f;
#pragma unroll
        for (int c = 0; c < 8; ++c) {
            const unsigned cx = x0 + (c & 1);
            const unsigned cy = y0 + ((c >> 1) & 1);
            const unsigned cz = z0 + ((c >> 2) & 1);
            unsigned idx;
            if (l < 5) {
                const unsigned s = res + 1u;
                idx = cx + cy * s + cz * (s * s);
            } else {
                idx = (cx * 1u) ^ (cy * 2654435761u) ^ (cz * 805459861u);
                idx &= (unsigned)(TBL - 1);
            }
            const float w = ((c & 1) ? wx : 1.0f - wx) *
                            ((c & 2) ? wy : 1.0f - wy) *
                            ((c & 4) ? wz : 1.0f - wz);
            const float2 f = *reinterpret_cast<const float2*>(tb + 2u * idx);
            a0 = fmaf(f.x, w, a0);
            a1 = fmaf(f.y, w, a1);
        }
        enc[2 * l + 0] = a0;
        enc[2 * l + 1] = a1;
    }

    // ---------------- sigma MLP: enc(32) -> 64 -> 17 ----------------
    float h[64];
#pragma unroll
    for (int j = 0; j < 64; ++j) h[j] = 0.0f;
#pragma unroll
    for (int k = 0; k < 32; ++k) {
        const float e = enc[k];
#pragma unroll
        for (int j = 0; j < 64; ++j) h[j] = fmaf(e, ws1[k * 64 + j], h[j]);
    }
#pragma unroll
    for (int j = 0; j < 64; ++j) h[j] = relu_f(h[j]);
    // enc[] dead from here

    float geo[17];
#pragma unroll
    for (int j = 0; j < 17; ++j) geo[j] = 0.0f;
#pragma unroll
    for (int k = 0; k < 64; ++k) {
        const float e = h[k];
#pragma unroll
        for (int j = 0; j < 17; ++j) geo[j] = fmaf(e, ws2[k * 17 + j], geo[j]);
    }
    // store sigma now (frees nothing big, but overlaps the store with compute)
    out[3 * (size_t)n + (size_t)i] = relu_f(geo[0]);
    // h[] dead from here

    // ---------------- SH deg-4 of dir*2-1 (loaded late to keep encode phase slim) ----------------
    const float dx = dirv[3 * (size_t)i + 0] * 2.0f - 1.0f;
    const float dy = dirv[3 * (size_t)i + 1] * 2.0f - 1.0f;
    const float dz = dirv[3 * (size_t)i + 2] * 2.0f - 1.0f;
    const float x2 = dx * dx, y2 = dy * dy, z2 = dz * dz;
    const float xy = dx * dy, yz = dy * dz, xz = dx * dz;

    float sh[16];
    sh[0]  = 0.28209479177387814f;
    sh[1]  = -0.48860251190291987f * dy;
    sh[2]  = 0.48860251190291987f * dz;
    sh[3]  = -0.48860251190291987f * dx;
    sh[4]  = 1.0925484305920792f * xy;
    sh[5]  = -1.0925484305920792f * yz;
    sh[6]  = 0.94617469575756f * z2 - 0.31539156525252f;
    sh[7]  = -1.0925484305920792f * xz;
    sh[8]  = 0.5462742152960396f * (x2 - y2);
    sh[9]  = 0.5900435899266435f * dy * (-3.0f * x2 + y2);
    sh[10] = 2.890611442640554f * xy * dz;
    sh[11] = 0.4570457994644657f * dy * (1.0f - 5.0f * z2);
    sh[12] = 0.3731763325901154f * dz * (5.0f * z2 - 3.0f);
    sh[13] = 0.4570457994644657f * dx * (1.0f - 5.0f * z2);
    sh[14] = 1.445305721320277f * dz * (x2 - y2);
    sh[15] = 0.5900435899266435f * dx * (-x2 + 3.0f * y2);

    // ---------------- rgb MLP: [sh(16) | geo[1..17](16)] -> 64 -> 64 -> 3 ----------------
    float g[64];
#pragma unroll
    for (int j = 0; j < 64; ++j) g[j] = 0.0f;
#pragma unroll
    for (int k = 0; k < 16; ++k) {
        const float e = sh[k];
#pragma unroll
        for (int j = 0; j < 64; ++j) g[j] = fmaf(e, wr1[k * 64 + j], g[j]);
    }
#pragma unroll
    for (int k = 16; k < 32; ++k) {
        const float e = geo[k - 15];   // geo_feat[k-16] = geo[k-16+1]
#pragma unroll
        for (int j = 0; j < 64; ++j) g[j] = fmaf(e, wr1[k * 64 + j], g[j]);
    }
#pragma unroll
    for (int j = 0; j < 64; ++j) g[j] = relu_f(g[j]);
    // sh[], geo[] dead from here

    // rgb layer 2 computed in two 32-neuron halves to cap live registers at ~g[64]+32
    float r0 = 0.0f, r1 = 0.0f, r2 = 0.0f;
#pragma unroll
    for (int half = 0; half < 2; ++half) {
        const int j0 = half * 32;
        float g2h[32];
#pragma unroll
        for (int j = 0; j < 32; ++j) g2h[j] = 0.0f;
#pragma unroll
        for (int k = 0; k < 64; ++k) {
            const float e = g[k];
#pragma unroll
            for (int j = 0; j < 32; ++j) g2h[j] = fmaf(e, wr2[k * 64 + j0 + j], g2h[j]);
        }
#pragma unroll
        for (int j = 0; j < 32; ++j) {
            const float e = relu_f(g2h[j]);
            r0 = fmaf(e, wr3[(j0 + j) * 3 + 0], r0);
            r1 = fmaf(e, wr3[(j0 + j) * 3 + 1], r1);
            r2 = fmaf(e, wr3[(j0 + j) * 3 + 2], r2);
        }
    }

    // ---------------- outputs: sigmoid(rgb) (N,3); relu(sigma) stored above ----------------
    out[3 * (size_t)i + 0] = 1.0f / (1.0f + __expf(-r0));
    out[3 * (size_t)i + 1] = 1.0f / (1.0f + __expf(-r1));
    out[3 * (size_t)i + 2] = 1.0f / (1.0f + __expf(-r2));
}

extern "C" void kernel_launch(void* const* d_in, const int* in_sizes, int n_in,
                              void* d_out, int out_size, void* d_ws, size_t ws_size,
                              hipStream_t stream)
{
    const float* xyz   = (const float*)d_in[0];
    const float* dirv  = (const float*)d_in[1];
    const float* table = (const float*)d_in[2];
    const float* ws1   = (const float*)d_in[3];
    const float* ws2   = (const float*)d_in[4];
    const float* wr1   = (const float*)d_in[5];
    const float* wr2   = (const float*)d_in[6];
    const float* wr3   = (const float*)d_in[7];
    float* out = (float*)d_out;

    const int n = in_sizes[0] / 3;
    dim3 block(256), grid((n + 255) / 256);
    hipLaunchKernelGGL(nerf_fused, grid, block, 0, stream,
                       xyz, dirv, table, ws1, ws2, wr1, wr2, wr3, out, n);
}